// Round 1
// baseline (584.997 us; speedup 1.0000x reference)
//
#include <hip/hip_runtime.h>
#include <cstdint>

#define NN 32768          // total nodes
#define NE 524288         // edges (before self-loops)
#define FEAT 256
#define HID 16

// ---------------- CSR build ----------------
__global__ void hist_kernel(const int* __restrict__ dst, int* __restrict__ deg) {
    int e = blockIdx.x * blockDim.x + threadIdx.x;
    if (e < NE) atomicAdd(&deg[dst[e]], 1);
}

__global__ __launch_bounds__(1024) void scan_kernel(const int* __restrict__ deg,
                                                    int* __restrict__ offs,
                                                    int* __restrict__ cur) {
    __shared__ int sums[1024];
    int t = threadIdx.x;
    int base = t * 32;
    int local[32];
    int s = 0;
    #pragma unroll
    for (int i = 0; i < 32; ++i) { local[i] = s; s += deg[base + i] + 1; } // +1 self-loop
    sums[t] = s;
    __syncthreads();
    int own = s;
    for (int o = 1; o < 1024; o <<= 1) {
        int v = (t >= o) ? sums[t - o] : 0;
        __syncthreads();
        sums[t] += v;
        __syncthreads();
    }
    int ex = sums[t] - own;   // exclusive prefix
    #pragma unroll
    for (int i = 0; i < 32; ++i) {
        int v = ex + local[i];
        offs[base + i] = v;
        cur[base + i] = v;
    }
    if (t == 1023) offs[NN] = sums[1023];
}

__global__ void scatter_kernel(const int* __restrict__ dst, int* __restrict__ cur,
                               int* __restrict__ csr) {
    int g = blockIdx.x * blockDim.x + threadIdx.x;
    if (g < NE) {
        int pos = atomicAdd(&cur[dst[g]], 1);
        csr[pos] = g;
    } else if (g < NE + NN) {
        int i = g - NE;
        int pos = atomicAdd(&cur[i], 1);
        csr[pos] = g;               // eid = NE + i encodes self-loop
    }
}

// ---------------- p = x @ w1 + 0.5*b1  ([NN,16]) ----------------
__global__ __launch_bounds__(256) void pk_kernel(const float* __restrict__ x,
                                                 const float* __restrict__ w1,
                                                 const float* __restrict__ b1,
                                                 float* __restrict__ p) {
    __shared__ float w1s[16 * 260];   // transposed [j][k], pad to 260
    int t = threadIdx.x;
    for (int u = t; u < 4096; u += 256) {
        int k = u >> 4, j = u & 15;
        w1s[j * 260 + k] = w1[u];
    }
    __syncthreads();
    int gid = blockIdx.x * 256 + t;
    int i = gid >> 4, j = gid & 15;
    float acc = 0.5f * b1[j];
    const float* xr = x + (size_t)i * FEAT;
    const float* wr = w1s + j * 260;
    #pragma unroll 8
    for (int k = 0; k < 256; k += 4) {
        float4 xv = *(const float4*)(xr + k);
        float4 wv = *(const float4*)(wr + k);
        acc = fmaf(xv.x, wv.x, acc);
        acc = fmaf(xv.y, wv.y, acc);
        acc = fmaf(xv.z, wv.z, acc);
        acc = fmaf(xv.w, wv.w, acc);
    }
    p[gid] = acc;
}

// ---------------- fused edge MLP + aggregation: one wave per node ----------------
#define MSG_J(hcomp, idx)                         \
    tt.x = fmaf(hcomp, w2r[idx].x, tt.x);         \
    tt.y = fmaf(hcomp, w2r[idx].y, tt.y);         \
    tt.z = fmaf(hcomp, w2r[idx].z, tt.z);         \
    tt.w = fmaf(hcomp, w2r[idx].w, tt.w);

__global__ __launch_bounds__(256) void edge_kernel(const float* __restrict__ p,
                                                   const float* __restrict__ w2,
                                                   const float* __restrict__ b2,
                                                   const int* __restrict__ csr,
                                                   const int* __restrict__ offs,
                                                   const int* __restrict__ esrc,
                                                   float* __restrict__ out) {
    __shared__ float h_lds[4][64];
    int w = threadIdx.x >> 6;
    int lane = threadIdx.x & 63;
    int node = blockIdx.x * 4 + w;
    int g = lane >> 4;       // edge slot within chunk of 4
    int j = lane & 15;       // hidden index

    // each lane owns output columns k = 4*lane .. 4*lane+3
    float4 w2r[16];
    #pragma unroll
    for (int jj = 0; jj < 16; ++jj)
        w2r[jj] = *(const float4*)(w2 + jj * FEAT + 4 * lane);
    float4 b2r = *(const float4*)(b2 + 4 * lane);

    float pi = p[node * HID + j];
    int rs = offs[node], re = offs[node + 1];
    float4 acc = make_float4(0.f, 0.f, 0.f, 0.f);

    for (int c = rs; c < re; c += 4) {
        int idx = c + g;
        int eid = csr[idx < re ? idx : (re - 1)];
        int s = (eid < NE) ? esrc[eid] : (eid - NE);
        float hv = fmaxf(p[s * HID + j] + pi, 0.f);   // h for edge g, component j
        h_lds[w][lane] = hv;
        int nv = re - c; if (nv > 4) nv = 4;
        for (int e2 = 0; e2 < nv; ++e2) {
            const float* hb = &h_lds[w][e2 * 16];
            float4 h0 = *(const float4*)(hb);
            float4 h1 = *(const float4*)(hb + 4);
            float4 h2 = *(const float4*)(hb + 8);
            float4 h3 = *(const float4*)(hb + 12);
            float4 tt = b2r;
            MSG_J(h0.x, 0)  MSG_J(h0.y, 1)  MSG_J(h0.z, 2)  MSG_J(h0.w, 3)
            MSG_J(h1.x, 4)  MSG_J(h1.y, 5)  MSG_J(h1.z, 6)  MSG_J(h1.w, 7)
            MSG_J(h2.x, 8)  MSG_J(h2.y, 9)  MSG_J(h2.z, 10) MSG_J(h2.w, 11)
            MSG_J(h3.x, 12) MSG_J(h3.y, 13) MSG_J(h3.z, 14) MSG_J(h3.w, 15)
            acc.x += fmaxf(tt.x, 0.f);
            acc.y += fmaxf(tt.y, 0.f);
            acc.z += fmaxf(tt.z, 0.f);
            acc.w += fmaxf(tt.w, 0.f);
        }
    }
    *(float4*)(out + (size_t)node * FEAT + 4 * lane) = acc;
}

// ---------------- readout GEMM1: y1pre += y[256,32768] @ w1[32768,64] (split-K) ----------------
__global__ __launch_bounds__(256) void ro1_kernel(const float* __restrict__ y,
                                                  const float* __restrict__ w1,
                                                  float* __restrict__ y1pre) {
    int m = threadIdx.x;                 // all 256 rows in every block
    int kb = blockIdx.x * 128;           // 256 blocks * 128 = 32768
    float acc[64];
    #pragma unroll
    for (int n = 0; n < 64; ++n) acc[n] = 0.f;
    const float* yr = y + (size_t)m * 32768 + kb;
    #pragma unroll 4
    for (int k = 0; k < 128; k += 4) {
        float4 yv = *(const float4*)(yr + k);
        const float* w0 = w1 + (size_t)(kb + k) * 64;
        #pragma unroll
        for (int n = 0; n < 64; ++n) acc[n] = fmaf(yv.x, w0[n], acc[n]);
        #pragma unroll
        for (int n = 0; n < 64; ++n) acc[n] = fmaf(yv.y, w0[64 + n], acc[n]);
        #pragma unroll
        for (int n = 0; n < 64; ++n) acc[n] = fmaf(yv.z, w0[128 + n], acc[n]);
        #pragma unroll
        for (int n = 0; n < 64; ++n) acc[n] = fmaf(yv.w, w0[192 + n], acc[n]);
    }
    #pragma unroll
    for (int n = 0; n < 64; ++n) atomicAdd(&y1pre[m * 64 + n], acc[n]);
}

__global__ void relub_kernel(const float* __restrict__ y1pre, const float* __restrict__ b1,
                             float* __restrict__ y1) {
    int i = blockIdx.x * 256 + threadIdx.x;
    y1[i] = fmaxf(y1pre[i] + b1[i & 63], 0.f);
}

// ---------------- readout GEMM2: out = relu(y1[256,64] @ w2[64,16384] + b2) ----------------
__global__ __launch_bounds__(256) void ro2_kernel(const float* __restrict__ y1,
                                                  const float* __restrict__ w2,
                                                  const float* __restrict__ b2,
                                                  float* __restrict__ out) {
    int mt = blockIdx.x >> 6;            // 4 m-tiles of 64
    int nt = blockIdx.x & 63;            // 64 n-tiles of 256
    int n = nt * 256 + threadIdx.x;
    float w2r[64];
    #pragma unroll
    for (int jj = 0; jj < 64; ++jj) w2r[jj] = w2[(size_t)jj * 16384 + n];
    float bb = b2[n];
    for (int m = mt * 64; m < mt * 64 + 64; ++m) {
        const float* yr = y1 + m * 64;   // uniform -> scalar loads
        float acc = bb;
        #pragma unroll
        for (int jj = 0; jj < 64; ++jj) acc = fmaf(yr[jj], w2r[jj], acc);
        out[(size_t)m * 16384 + n] = fmaxf(acc, 0.f);
    }
}

extern "C" void kernel_launch(void* const* d_in, const int* in_sizes, int n_in,
                              void* d_out, int out_size, void* d_ws, size_t ws_size,
                              hipStream_t stream) {
    (void)in_sizes; (void)n_in; (void)out_size; (void)ws_size;
    const float* x      = (const float*)d_in[0];
    const int*   ei     = (const int*)d_in[1];     // [2, NE] : row0 src, row1 dst
    const float* mp1_w1 = (const float*)d_in[2];
    const float* mp1_b1 = (const float*)d_in[3];
    const float* mp1_w2 = (const float*)d_in[4];
    const float* mp1_b2 = (const float*)d_in[5];
    const float* mp2_w1 = (const float*)d_in[6];
    const float* mp2_b1 = (const float*)d_in[7];
    const float* mp2_w2 = (const float*)d_in[8];
    const float* mp2_b2 = (const float*)d_in[9];
    const float* ro_w1  = (const float*)d_in[10];
    const float* ro_b1  = (const float*)d_in[11];
    const float* ro_w2  = (const float*)d_in[12];
    const float* ro_b2  = (const float*)d_in[13];
    float* out = (float*)d_out;

    // workspace carve-up (~38.3 MB)
    float* p     = (float*)d_ws;          // NN*16
    float* x1    = p + (size_t)NN * HID;  // NN*256 (layer1 out; layer2 out aliases)
    float* y1pre = x1 + (size_t)NN * FEAT;
    float* y1    = y1pre + 16384;
    int*   deg   = (int*)(y1 + 16384);
    int*   offs  = deg + NN;
    int*   cur   = offs + NN + 1;
    int*   csr   = cur + NN;              // NE + NN entries

    const int* dst = ei + NE;

    hipMemsetAsync(deg, 0, NN * sizeof(int), stream);
    hipMemsetAsync(y1pre, 0, 16384 * sizeof(float), stream);

    hist_kernel<<<NE / 256, 256, 0, stream>>>(dst, deg);
    scan_kernel<<<1, 1024, 0, stream>>>(deg, offs, cur);
    scatter_kernel<<<(NE + NN) / 256, 256, 0, stream>>>(dst, cur, csr);

    // layer 1
    pk_kernel<<<(NN * HID) / 256, 256, 0, stream>>>(x, mp1_w1, mp1_b1, p);
    edge_kernel<<<NN / 4, 256, 0, stream>>>(p, mp1_w2, mp1_b2, csr, offs, ei, x1);
    // layer 2 (p recomputed from x1; output overwrites x1 — safe, edge_kernel doesn't read x1)
    pk_kernel<<<(NN * HID) / 256, 256, 0, stream>>>(x1, mp2_w1, mp2_b1, p);
    edge_kernel<<<NN / 4, 256, 0, stream>>>(p, mp2_w2, mp2_b2, csr, offs, ei, x1);

    // readout
    ro1_kernel<<<256, 256, 0, stream>>>(x1, ro_w1, y1pre);
    relub_kernel<<<64, 256, 0, stream>>>(y1pre, ro_b1, y1);
    ro2_kernel<<<256, 256, 0, stream>>>(y1, ro_w2, ro_b2, out);
}

// Round 2
// 473.303 us; speedup vs baseline: 1.2360x; 1.2360x over previous
//
#include <hip/hip_runtime.h>
#include <cstdint>

#define NN 32768          // total nodes
#define NE 524288         // edges (before self-loops)
#define FEAT 256
#define HID 16

// ---------------- CSR build ----------------
__global__ void hist_kernel(const int* __restrict__ dst, int* __restrict__ deg) {
    int e = blockIdx.x * blockDim.x + threadIdx.x;
    if (e < NE) atomicAdd(&deg[dst[e]], 1);
}

__global__ __launch_bounds__(1024) void scan_kernel(const int* __restrict__ deg,
                                                    int* __restrict__ offs,
                                                    int* __restrict__ cur) {
    __shared__ int sums[1024];
    int t = threadIdx.x;
    int base = t * 32;
    int local[32];
    int s = 0;
    #pragma unroll
    for (int i = 0; i < 32; ++i) { local[i] = s; s += deg[base + i] + 1; } // +1 self-loop
    sums[t] = s;
    __syncthreads();
    int own = s;
    for (int o = 1; o < 1024; o <<= 1) {
        int v = (t >= o) ? sums[t - o] : 0;
        __syncthreads();
        sums[t] += v;
        __syncthreads();
    }
    int ex = sums[t] - own;   // exclusive prefix
    #pragma unroll
    for (int i = 0; i < 32; ++i) {
        int v = ex + local[i];
        offs[base + i] = v;
        cur[base + i] = v;
    }
    if (t == 1023) offs[NN] = sums[1023];
}

__global__ void scatter_kernel(const int* __restrict__ dst, int* __restrict__ cur,
                               int* __restrict__ csr) {
    int g = blockIdx.x * blockDim.x + threadIdx.x;
    if (g < NE) {
        int pos = atomicAdd(&cur[dst[g]], 1);
        csr[pos] = g;
    } else if (g < NE + NN) {
        int i = g - NE;
        int pos = atomicAdd(&cur[i], 1);
        csr[pos] = g;               // eid = NE + i encodes self-loop
    }
}

// ---------------- p = x @ w1 + 0.5*b1  ([NN,16]) ----------------
__global__ __launch_bounds__(256) void pk_kernel(const float* __restrict__ x,
                                                 const float* __restrict__ w1,
                                                 const float* __restrict__ b1,
                                                 float* __restrict__ p) {
    __shared__ float w1s[16 * 260];   // transposed [j][k], pad to 260
    int t = threadIdx.x;
    for (int u = t; u < 4096; u += 256) {
        int k = u >> 4, j = u & 15;
        w1s[j * 260 + k] = w1[u];
    }
    __syncthreads();
    int gid = blockIdx.x * 256 + t;
    int i = gid >> 4, j = gid & 15;
    float acc = 0.5f * b1[j];
    const float* xr = x + (size_t)i * FEAT;
    const float* wr = w1s + j * 260;
    #pragma unroll 8
    for (int k = 0; k < 256; k += 4) {
        float4 xv = *(const float4*)(xr + k);
        float4 wv = *(const float4*)(wr + k);
        acc = fmaf(xv.x, wv.x, acc);
        acc = fmaf(xv.y, wv.y, acc);
        acc = fmaf(xv.z, wv.z, acc);
        acc = fmaf(xv.w, wv.w, acc);
    }
    p[gid] = acc;
}

// ---------------- fused edge MLP + aggregation: one wave per node ----------------
#define MSG_J(hcomp, idx)                         \
    tt.x = fmaf(hcomp, w2r[idx].x, tt.x);         \
    tt.y = fmaf(hcomp, w2r[idx].y, tt.y);         \
    tt.z = fmaf(hcomp, w2r[idx].z, tt.z);         \
    tt.w = fmaf(hcomp, w2r[idx].w, tt.w);

__global__ __launch_bounds__(256) void edge_kernel(const float* __restrict__ p,
                                                   const float* __restrict__ w2,
                                                   const float* __restrict__ b2,
                                                   const int* __restrict__ csr,
                                                   const int* __restrict__ offs,
                                                   const int* __restrict__ esrc,
                                                   float* __restrict__ out) {
    __shared__ float h_lds[4][64];
    int w = threadIdx.x >> 6;
    int lane = threadIdx.x & 63;
    int node = blockIdx.x * 4 + w;
    int g = lane >> 4;       // edge slot within chunk of 4
    int j = lane & 15;       // hidden index

    // each lane owns output columns k = 4*lane .. 4*lane+3
    float4 w2r[16];
    #pragma unroll
    for (int jj = 0; jj < 16; ++jj)
        w2r[jj] = *(const float4*)(w2 + jj * FEAT + 4 * lane);
    float4 b2r = *(const float4*)(b2 + 4 * lane);

    float pi = p[node * HID + j];
    int rs = offs[node], re = offs[node + 1];
    float4 acc = make_float4(0.f, 0.f, 0.f, 0.f);

    for (int c = rs; c < re; c += 4) {
        int idx = c + g;
        int eid = csr[idx < re ? idx : (re - 1)];
        int s = (eid < NE) ? esrc[eid] : (eid - NE);
        float hv = fmaxf(p[s * HID + j] + pi, 0.f);   // h for edge g, component j
        h_lds[w][lane] = hv;
        int nv = re - c; if (nv > 4) nv = 4;
        for (int e2 = 0; e2 < nv; ++e2) {
            const float* hb = &h_lds[w][e2 * 16];
            float4 h0 = *(const float4*)(hb);
            float4 h1 = *(const float4*)(hb + 4);
            float4 h2 = *(const float4*)(hb + 8);
            float4 h3 = *(const float4*)(hb + 12);
            float4 tt = b2r;
            MSG_J(h0.x, 0)  MSG_J(h0.y, 1)  MSG_J(h0.z, 2)  MSG_J(h0.w, 3)
            MSG_J(h1.x, 4)  MSG_J(h1.y, 5)  MSG_J(h1.z, 6)  MSG_J(h1.w, 7)
            MSG_J(h2.x, 8)  MSG_J(h2.y, 9)  MSG_J(h2.z, 10) MSG_J(h2.w, 11)
            MSG_J(h3.x, 12) MSG_J(h3.y, 13) MSG_J(h3.z, 14) MSG_J(h3.w, 15)
            acc.x += fmaxf(tt.x, 0.f);
            acc.y += fmaxf(tt.y, 0.f);
            acc.z += fmaxf(tt.z, 0.f);
            acc.w += fmaxf(tt.w, 0.f);
        }
    }
    *(float4*)(out + (size_t)node * FEAT + 4 * lane) = acc;
}

// ---------------- readout GEMM1: y1pre += y[256,32768] @ w1[32768,64] ----------------
// grid = 32 m-tiles (8 rows) x 8 k-tiles (4096); within block, K split 4-way by wave.
// Each thread: 8 accumulators (n = lane, m = 0..7). NO per-thread acc array > 8.
__global__ __launch_bounds__(256) void ro1_kernel(const float* __restrict__ y,
                                                  const float* __restrict__ w1,
                                                  float* __restrict__ y1pre) {
    int mb = blockIdx.x >> 3;            // 0..31
    int kb = blockIdx.x & 7;             // 0..7
    int ks = __builtin_amdgcn_readfirstlane(threadIdx.x >> 6);  // wave id 0..3 (SGPR)
    int n  = threadIdx.x & 63;

    const float* yb = y + (size_t)(mb * 8) * 32768 + kb * 4096 + ks * 1024;
    const float* wb = w1 + (size_t)(kb * 4096 + ks * 1024) * 64 + n;

    float acc[8] = {0.f, 0.f, 0.f, 0.f, 0.f, 0.f, 0.f, 0.f};
    #pragma unroll 2
    for (int k = 0; k < 1024; k += 4) {
        float w0 = wb[(size_t)(k + 0) * 64];
        float w1v = wb[(size_t)(k + 1) * 64];
        float w2v = wb[(size_t)(k + 2) * 64];
        float w3v = wb[(size_t)(k + 3) * 64];
        #pragma unroll
        for (int m = 0; m < 8; ++m) {
            float4 yv = *(const float4*)(yb + (size_t)m * 32768 + k);  // wave-uniform addr
            acc[m] = fmaf(yv.x, w0, acc[m]);
            acc[m] = fmaf(yv.y, w1v, acc[m]);
            acc[m] = fmaf(yv.z, w2v, acc[m]);
            acc[m] = fmaf(yv.w, w3v, acc[m]);
        }
    }

    __shared__ float red[4][64][8];      // 8 KB
    #pragma unroll
    for (int m = 0; m < 8; ++m) red[ks][n][m] = acc[m];
    __syncthreads();
    int t = threadIdx.x;
    #pragma unroll
    for (int u = t; u < 512; u += 256) {
        int m = u >> 6, nn = u & 63;
        float v = red[0][nn][m] + red[1][nn][m] + red[2][nn][m] + red[3][nn][m];
        atomicAdd(&y1pre[(mb * 8 + m) * 64 + nn], v);
    }
}

__global__ void relub_kernel(const float* __restrict__ y1pre, const float* __restrict__ b1,
                             float* __restrict__ y1) {
    int i = blockIdx.x * 256 + threadIdx.x;
    y1[i] = fmaxf(y1pre[i] + b1[i & 63], 0.f);
}

// ---------------- readout GEMM2: out = relu(y1[256,64] @ w2[64,16384] + b2) ----------------
__global__ __launch_bounds__(256) void ro2_kernel(const float* __restrict__ y1,
                                                  const float* __restrict__ w2,
                                                  const float* __restrict__ b2,
                                                  float* __restrict__ out) {
    int mt = blockIdx.x >> 6;            // 4 m-tiles of 64
    int nt = blockIdx.x & 63;            // 64 n-tiles of 256
    int n = nt * 256 + threadIdx.x;
    float w2r[64];
    #pragma unroll
    for (int jj = 0; jj < 64; ++jj) w2r[jj] = w2[(size_t)jj * 16384 + n];
    float bb = b2[n];
    for (int m = mt * 64; m < mt * 64 + 64; ++m) {
        const float* yr = y1 + m * 64;   // uniform -> scalar loads
        float acc = bb;
        #pragma unroll
        for (int jj = 0; jj < 64; ++jj) acc = fmaf(yr[jj], w2r[jj], acc);
        out[(size_t)m * 16384 + n] = fmaxf(acc, 0.f);
    }
}

extern "C" void kernel_launch(void* const* d_in, const int* in_sizes, int n_in,
                              void* d_out, int out_size, void* d_ws, size_t ws_size,
                              hipStream_t stream) {
    (void)in_sizes; (void)n_in; (void)out_size; (void)ws_size;
    const float* x      = (const float*)d_in[0];
    const int*   ei     = (const int*)d_in[1];     // [2, NE] : row0 src, row1 dst
    const float* mp1_w1 = (const float*)d_in[2];
    const float* mp1_b1 = (const float*)d_in[3];
    const float* mp1_w2 = (const float*)d_in[4];
    const float* mp1_b2 = (const float*)d_in[5];
    const float* mp2_w1 = (const float*)d_in[6];
    const float* mp2_b1 = (const float*)d_in[7];
    const float* mp2_w2 = (const float*)d_in[8];
    const float* mp2_b2 = (const float*)d_in[9];
    const float* ro_w1  = (const float*)d_in[10];
    const float* ro_b1  = (const float*)d_in[11];
    const float* ro_w2  = (const float*)d_in[12];
    const float* ro_b2  = (const float*)d_in[13];
    float* out = (float*)d_out;

    // workspace carve-up (~38.3 MB)
    float* p     = (float*)d_ws;          // NN*16
    float* x1    = p + (size_t)NN * HID;  // NN*256 (layer1 out; layer2 out aliases)
    float* y1pre = x1 + (size_t)NN * FEAT;
    float* y1    = y1pre + 16384;
    int*   deg   = (int*)(y1 + 16384);
    int*   offs  = deg + NN;
    int*   cur   = offs + NN + 1;
    int*   csr   = cur + NN;              // NE + NN entries

    const int* dst = ei + NE;

    hipMemsetAsync(deg, 0, NN * sizeof(int), stream);
    hipMemsetAsync(y1pre, 0, 16384 * sizeof(float), stream);

    hist_kernel<<<NE / 256, 256, 0, stream>>>(dst, deg);
    scan_kernel<<<1, 1024, 0, stream>>>(deg, offs, cur);
    scatter_kernel<<<(NE + NN) / 256, 256, 0, stream>>>(dst, cur, csr);

    // layer 1
    pk_kernel<<<(NN * HID) / 256, 256, 0, stream>>>(x, mp1_w1, mp1_b1, p);
    edge_kernel<<<NN / 4, 256, 0, stream>>>(p, mp1_w2, mp1_b2, csr, offs, ei, x1);
    // layer 2 (p recomputed from x1; output overwrites x1 — safe, edge_kernel doesn't read x1)
    pk_kernel<<<(NN * HID) / 256, 256, 0, stream>>>(x1, mp2_w1, mp2_b1, p);
    edge_kernel<<<NN / 4, 256, 0, stream>>>(p, mp2_w2, mp2_b2, csr, offs, ei, x1);

    // readout
    ro1_kernel<<<256, 256, 0, stream>>>(x1, ro_w1, y1pre);
    relub_kernel<<<64, 256, 0, stream>>>(y1pre, ro_b1, y1);
    ro2_kernel<<<256, 256, 0, stream>>>(y1, ro_w2, ro_b2, out);
}

// Round 4
// 354.938 us; speedup vs baseline: 1.6482x; 1.3335x over previous
//
#include <hip/hip_runtime.h>
#include <cstdint>

#define NN 32768          // total nodes
#define NE 524288         // edges (before self-loops)
#define FEAT 256
#define HID 16

// ---------------- CSR build ----------------
__global__ void hist_kernel(const int* __restrict__ dst, int* __restrict__ deg) {
    int e = blockIdx.x * blockDim.x + threadIdx.x;
    if (e < NE) atomicAdd(&deg[dst[e]], 1);
}

__global__ __launch_bounds__(1024) void scan_kernel(const int* __restrict__ deg,
                                                    int* __restrict__ offs,
                                                    int* __restrict__ cur) {
    __shared__ int sums[1024];
    int t = threadIdx.x;
    int base = t * 32;
    int local[32];
    int s = 0;
    #pragma unroll
    for (int i = 0; i < 32; ++i) { local[i] = s; s += deg[base + i] + 1; } // +1 self-loop
    sums[t] = s;
    __syncthreads();
    int own = s;
    for (int o = 1; o < 1024; o <<= 1) {
        int v = (t >= o) ? sums[t - o] : 0;
        __syncthreads();
        sums[t] += v;
        __syncthreads();
    }
    int ex = sums[t] - own;   // exclusive prefix
    #pragma unroll
    for (int i = 0; i < 32; ++i) {
        int v = ex + local[i];
        offs[base + i] = v;
        cur[base + i] = v;
    }
    if (t == 1023) offs[NN] = sums[1023];
}

__global__ void scatter_kernel(const int* __restrict__ dst, int* __restrict__ cur,
                               int* __restrict__ csr) {
    int g = blockIdx.x * blockDim.x + threadIdx.x;
    if (g < NE) {
        int pos = atomicAdd(&cur[dst[g]], 1);
        csr[pos] = g;
    } else if (g < NE + NN) {
        int i = g - NE;
        int pos = atomicAdd(&cur[i], 1);
        csr[pos] = g;               // eid = NE + i encodes self-loop
    }
}

// ---------------- p = x @ w1 + 0.5*b1  ([NN,16]) ----------------
__global__ __launch_bounds__(256) void pk_kernel(const float* __restrict__ x,
                                                 const float* __restrict__ w1,
                                                 const float* __restrict__ b1,
                                                 float* __restrict__ p) {
    __shared__ float w1s[16 * 260];   // transposed [j][k], pad to 260
    int t = threadIdx.x;
    for (int u = t; u < 4096; u += 256) {
        int k = u >> 4, j = u & 15;
        w1s[j * 260 + k] = w1[u];
    }
    __syncthreads();
    int gid = blockIdx.x * 256 + t;
    int i = gid >> 4, j = gid & 15;
    float acc = 0.5f * b1[j];
    const float* xr = x + (size_t)i * FEAT;
    const float* wr = w1s + j * 260;
    #pragma unroll 8
    for (int k = 0; k < 256; k += 4) {
        float4 xv = *(const float4*)(xr + k);
        float4 wv = *(const float4*)(wr + k);
        acc = fmaf(xv.x, wv.x, acc);
        acc = fmaf(xv.y, wv.y, acc);
        acc = fmaf(xv.z, wv.z, acc);
        acc = fmaf(xv.w, wv.w, acc);
    }
    p[gid] = acc;
}

// ---------------- fused edge MLP + aggregation: one wave per node ----------------
#define MSG_J(hcomp, idx)                         \
    tt.x = fmaf(hcomp, w2r[idx].x, tt.x);         \
    tt.y = fmaf(hcomp, w2r[idx].y, tt.y);         \
    tt.z = fmaf(hcomp, w2r[idx].z, tt.z);         \
    tt.w = fmaf(hcomp, w2r[idx].w, tt.w);

__global__ __launch_bounds__(256) void edge_kernel(const float* __restrict__ p,
                                                   const float* __restrict__ w2,
                                                   const float* __restrict__ b2,
                                                   const int* __restrict__ csr,
                                                   const int* __restrict__ offs,
                                                   const int* __restrict__ esrc,
                                                   float* __restrict__ out) {
    __shared__ float h_lds[4][64];
    int w = threadIdx.x >> 6;
    int lane = threadIdx.x & 63;
    int node = blockIdx.x * 4 + w;
    int g = lane >> 4;       // edge slot within chunk of 4
    int j = lane & 15;       // hidden index

    // each lane owns output columns k = 4*lane .. 4*lane+3
    float4 w2r[16];
    #pragma unroll
    for (int jj = 0; jj < 16; ++jj)
        w2r[jj] = *(const float4*)(w2 + jj * FEAT + 4 * lane);
    float4 b2r = *(const float4*)(b2 + 4 * lane);

    float pi = p[node * HID + j];
    int rs = offs[node], re = offs[node + 1];
    float4 acc = make_float4(0.f, 0.f, 0.f, 0.f);

    for (int c = rs; c < re; c += 4) {
        int idx = c + g;
        int eid = csr[idx < re ? idx : (re - 1)];
        int s = (eid < NE) ? esrc[eid] : (eid - NE);
        float hv = fmaxf(p[s * HID + j] + pi, 0.f);   // h for edge g, component j
        h_lds[w][lane] = hv;
        int nv = re - c; if (nv > 4) nv = 4;
        for (int e2 = 0; e2 < nv; ++e2) {
            const float* hb = &h_lds[w][e2 * 16];
            float4 h0 = *(const float4*)(hb);
            float4 h1 = *(const float4*)(hb + 4);
            float4 h2 = *(const float4*)(hb + 8);
            float4 h3 = *(const float4*)(hb + 12);
            float4 tt = b2r;
            MSG_J(h0.x, 0)  MSG_J(h0.y, 1)  MSG_J(h0.z, 2)  MSG_J(h0.w, 3)
            MSG_J(h1.x, 4)  MSG_J(h1.y, 5)  MSG_J(h1.z, 6)  MSG_J(h1.w, 7)
            MSG_J(h2.x, 8)  MSG_J(h2.y, 9)  MSG_J(h2.z, 10) MSG_J(h2.w, 11)
            MSG_J(h3.x, 12) MSG_J(h3.y, 13) MSG_J(h3.z, 14) MSG_J(h3.w, 15)
            acc.x += fmaxf(tt.x, 0.f);
            acc.y += fmaxf(tt.y, 0.f);
            acc.z += fmaxf(tt.z, 0.f);
            acc.w += fmaxf(tt.w, 0.f);
        }
    }
    *(float4*)(out + (size_t)node * FEAT + 4 * lane) = acc;
}

// ---------------- readout GEMM1 partials: y1part[kb][256][64] ----------------
// grid = 16 mb x 32 kb = 512 blocks. Wave ks owns k-slice of 256.
// Lane l double-duties: k-offset for coalesced y loads, n-column for w1/acc.
// Wave-broadcast of y via v_readlane (no LDS pipe). Plain stores, no atomics.
__global__ __launch_bounds__(256) void ro1_kernel(const float* __restrict__ y,
                                                  const float* __restrict__ w1,
                                                  float* __restrict__ y1part) {
    int mb = blockIdx.x >> 5;            // 0..15
    int kb = blockIdx.x & 31;            // 0..31
    int t = threadIdx.x;
    int ks = t >> 6;                     // wave 0..3
    int lane = t & 63;                   // n column AND k-offset

    float acc[16];
    #pragma unroll
    for (int m = 0; m < 16; ++m) acc[m] = 0.f;

    int kslice = kb * 1024 + ks * 256;
    for (int c4 = 0; c4 < 4; ++c4) {
        int k0 = kslice + c4 * 64;
        float yv[16];
        #pragma unroll
        for (int m = 0; m < 16; ++m)
            yv[m] = y[(size_t)(mb * 16 + m) * 32768 + k0 + lane];   // coalesced
        const float* wp = w1 + (size_t)k0 * 64 + lane;
        #pragma unroll 8
        for (int kk = 0; kk < 64; ++kk) {
            float wv = wp[(size_t)kk * 64];                          // coalesced
            #pragma unroll
            for (int m = 0; m < 16; ++m) {
                float ys = __int_as_float(
                    __builtin_amdgcn_readlane(__float_as_int(yv[m]), kk));
                acc[m] = fmaf(ys, wv, acc[m]);
            }
        }
    }

    // 4-wave cross-k reduction: single write -> barrier -> read phase.
    __shared__ float red[4368];          // 256*17 + pad
    #pragma unroll
    for (int m = 0; m < 16; ++m) red[t * 17 + m] = acc[m];
    __syncthreads();
    #pragma unroll
    for (int i = 0; i < 4; ++i) {
        int u = t + i * 256;
        int m = u >> 6, nn = u & 63;
        float v = red[nn * 17 + m] + red[(64 + nn) * 17 + m]
                + red[(128 + nn) * 17 + m] + red[(192 + nn) * 17 + m];
        y1part[(size_t)kb * 16384 + (mb * 16 + m) * 64 + nn] = v;   // race-free
    }
}

// ---------------- combine partials + bias + relu ----------------
__global__ void relub_kernel(const float* __restrict__ y1part, const float* __restrict__ b1,
                             float* __restrict__ y1) {
    int i = blockIdx.x * 256 + threadIdx.x;
    float s = b1[i & 63];
    #pragma unroll 8
    for (int kb = 0; kb < 32; ++kb) s += y1part[(size_t)kb * 16384 + i];
    y1[i] = fmaxf(s, 0.f);
}

// ---------------- readout GEMM2: out = relu(y1[256,64] @ w2[64,16384] + b2) ----------------
// y1 tile staged in LDS (coalesced), read as broadcast ds_read_b128.
__global__ __launch_bounds__(256) void ro2_kernel(const float* __restrict__ y1,
                                                  const float* __restrict__ w2,
                                                  const float* __restrict__ b2,
                                                  float* __restrict__ out) {
    __shared__ float yls[64 * 68];       // 64 m-rows x 64 jj, stride 68 (16B-aligned)
    int mt = blockIdx.x >> 6;            // 4 m-tiles of 64
    int nt = blockIdx.x & 63;            // 64 n-tiles of 256
    int t = threadIdx.x;
    for (int u = t; u < 4096; u += 256) {
        int row = u >> 6, col = u & 63;
        yls[row * 68 + col] = y1[(mt * 64 + row) * 64 + col];       // coalesced
    }
    __syncthreads();

    int n = nt * 256 + t;
    float w2r[64];
    #pragma unroll
    for (int jj = 0; jj < 64; ++jj) w2r[jj] = w2[(size_t)jj * 16384 + n];
    float bb = b2[n];
    for (int m = 0; m < 64; ++m) {
        float acc = bb;
        const float* yr = &yls[m * 68];
        #pragma unroll
        for (int jj = 0; jj < 64; jj += 4) {
            float4 yv = *(const float4*)(yr + jj);                  // broadcast
            acc = fmaf(yv.x, w2r[jj],     acc);
            acc = fmaf(yv.y, w2r[jj + 1], acc);
            acc = fmaf(yv.z, w2r[jj + 2], acc);
            acc = fmaf(yv.w, w2r[jj + 3], acc);
        }
        out[(size_t)(mt * 64 + m) * 16384 + n] = fmaxf(acc, 0.f);
    }
}

extern "C" void kernel_launch(void* const* d_in, const int* in_sizes, int n_in,
                              void* d_out, int out_size, void* d_ws, size_t ws_size,
                              hipStream_t stream) {
    (void)in_sizes; (void)n_in; (void)out_size; (void)ws_size;
    const float* x      = (const float*)d_in[0];
    const int*   ei     = (const int*)d_in[1];     // [2, NE] : row0 src, row1 dst
    const float* mp1_w1 = (const float*)d_in[2];
    const float* mp1_b1 = (const float*)d_in[3];
    const float* mp1_w2 = (const float*)d_in[4];
    const float* mp1_b2 = (const float*)d_in[5];
    const float* mp2_w1 = (const float*)d_in[6];
    const float* mp2_b1 = (const float*)d_in[7];
    const float* mp2_w2 = (const float*)d_in[8];
    const float* mp2_b2 = (const float*)d_in[9];
    const float* ro_w1  = (const float*)d_in[10];
    const float* ro_b1  = (const float*)d_in[11];
    const float* ro_w2  = (const float*)d_in[12];
    const float* ro_b2  = (const float*)d_in[13];
    float* out = (float*)d_out;

    // workspace carve-up. y1part (32*16384 = 524288 floats) ALIASES p:
    // p is dead after the last edge_kernel, before ro1 runs.
    float* p      = (float*)d_ws;          // NN*16 = 524288 floats
    float* y1part = p;                     // alias, 32*16384 = 524288 floats
    float* x1     = p + (size_t)NN * HID;  // NN*256
    float* y1     = x1 + (size_t)NN * FEAT;            // 16384
    int*   deg    = (int*)(y1 + 16384);
    int*   offs   = deg + NN;
    int*   cur    = offs + NN + 1;
    int*   csr    = cur + NN;              // NE + NN entries

    const int* dst = ei + NE;

    hipMemsetAsync(deg, 0, NN * sizeof(int), stream);

    hist_kernel<<<NE / 256, 256, 0, stream>>>(dst, deg);
    scan_kernel<<<1, 1024, 0, stream>>>(deg, offs, cur);
    scatter_kernel<<<(NE + NN) / 256, 256, 0, stream>>>(dst, cur, csr);

    // layer 1
    pk_kernel<<<(NN * HID) / 256, 256, 0, stream>>>(x, mp1_w1, mp1_b1, p);
    edge_kernel<<<NN / 4, 256, 0, stream>>>(p, mp1_w2, mp1_b2, csr, offs, ei, x1);
    // layer 2 (p recomputed from x1; output overwrites x1 — safe, edge_kernel doesn't read x1)
    pk_kernel<<<(NN * HID) / 256, 256, 0, stream>>>(x1, mp2_w1, mp2_b1, p);
    edge_kernel<<<NN / 4, 256, 0, stream>>>(p, mp2_w2, mp2_b2, csr, offs, ei, x1);

    // readout (p is dead now; y1part reuses its storage)
    ro1_kernel<<<512, 256, 0, stream>>>(x1, ro_w1, y1part);
    relub_kernel<<<64, 256, 0, stream>>>(y1part, ro_b1, y1);
    ro2_kernel<<<256, 256, 0, stream>>>(y1, ro_w2, ro_b2, out);
}

// Round 5
// 297.573 us; speedup vs baseline: 1.9659x; 1.1928x over previous
//
#include <hip/hip_runtime.h>
#include <hip/hip_bf16.h>
#include <cstdint>

#define NN 32768          // total nodes
#define NE 524288         // edges (before self-loops)
#define FEAT 256
#define HID 16
#define CSR_CAP (NE + 32 * NN)   // hard bound on padded CSR length (1,572,864)

typedef float f32x16 __attribute__((ext_vector_type(16)));
typedef short s16x8  __attribute__((ext_vector_type(8)));

// ---------------- CSR build ----------------
__global__ void hist_kernel(const int* __restrict__ dst, int* __restrict__ deg) {
    int e = blockIdx.x * blockDim.x + threadIdx.x;
    if (e < NE) atomicAdd(&deg[dst[e]], 1);
}

// padded scan: each node's segment length = ceil((deg+1)/32)*32
__global__ __launch_bounds__(1024) void scan_kernel(const int* __restrict__ deg,
                                                    int* __restrict__ offs,
                                                    int* __restrict__ cur) {
    __shared__ int sums[1024];
    int t = threadIdx.x;
    int base = t * 32;
    int local[32];
    int s = 0;
    #pragma unroll
    for (int i = 0; i < 32; ++i) {
        local[i] = s;
        s += (deg[base + i] + 32) & ~31;   // deg+1 self-loop, padded to mult of 32
    }
    sums[t] = s;
    __syncthreads();
    int own = s;
    for (int o = 1; o < 1024; o <<= 1) {
        int v = (t >= o) ? sums[t - o] : 0;
        __syncthreads();
        sums[t] += v;
        __syncthreads();
    }
    int ex = sums[t] - own;   // exclusive prefix
    #pragma unroll
    for (int i = 0; i < 32; ++i) {
        int v = ex + local[i];
        offs[base + i] = v;
        cur[base + i] = v;
    }
    if (t == 1023) offs[NN] = sums[1023];
}

// scatter resolved SRC node ids (ushort); pads remain 0xFFFF from memset
__global__ void scatter_kernel(const int* __restrict__ src, const int* __restrict__ dst,
                               int* __restrict__ cur, unsigned short* __restrict__ csrp) {
    int g = blockIdx.x * blockDim.x + threadIdx.x;
    if (g < NE) {
        int pos = atomicAdd(&cur[dst[g]], 1);
        csrp[pos] = (unsigned short)src[g];
    } else if (g < NE + NN) {
        int i = g - NE;
        int pos = atomicAdd(&cur[i], 1);
        csrp[pos] = (unsigned short)i;    // self-loop: src == node
    }
}

// ---------------- pack w2 into 32x32x16 MFMA B-fragments (bf16) ----------------
// B[k][n]: lane l holds col n = l&31, k = (l>>5)*8 + j. 8 col-tiles of 32.
__global__ void prepack_w2(const float* __restrict__ w2, unsigned short* __restrict__ w2p) {
    int t = threadIdx.x >> 6, l = threadIdx.x & 63;
    int c = l & 31, kh = l >> 5;
    s16x8 v;
    #pragma unroll
    for (int j = 0; j < 8; ++j) {
        float f = w2[(kh * 8 + j) * FEAT + t * 32 + c];
        __hip_bfloat16 hb = __float2bfloat16(f);
        v[j] = __builtin_bit_cast(short, hb);
    }
    *(s16x8*)(w2p + (size_t)(t * 64 + l) * 8) = v;
}

// ---------------- p = x @ w1 + 0.5*b1  ([NN,16]) ----------------
__global__ __launch_bounds__(256) void pk_kernel(const float* __restrict__ x,
                                                 const float* __restrict__ w1,
                                                 const float* __restrict__ b1,
                                                 float* __restrict__ p) {
    __shared__ float w1s[16 * 260];   // transposed [j][k], pad to 260
    int t = threadIdx.x;
    for (int u = t; u < 4096; u += 256) {
        int k = u >> 4, j = u & 15;
        w1s[j * 260 + k] = w1[u];
    }
    __syncthreads();
    int gid = blockIdx.x * 256 + t;
    int i = gid >> 4, j = gid & 15;
    float acc = 0.5f * b1[j];
    const float* xr = x + (size_t)i * FEAT;
    const float* wr = w1s + j * 260;
    #pragma unroll 8
    for (int k = 0; k < 256; k += 4) {
        float4 xv = *(const float4*)(xr + k);
        float4 wv = *(const float4*)(wr + k);
        acc = fmaf(xv.x, wv.x, acc);
        acc = fmaf(xv.y, wv.y, acc);
        acc = fmaf(xv.z, wv.z, acc);
        acc = fmaf(xv.w, wv.w, acc);
    }
    p[gid] = acc;
}

// ---------------- edge MLP + aggregation via MFMA: one wave per node ----------------
// Per 32-edge tile: A = h[32 edges][16] (hi/lo bf16 split), B_t = w2[16][32 cols].
// msg = relu(A@B + b2); node_acc[col] += sum_rows(msg). Pad rows give exactly
// relu(b2), cancelled by -npad*relu(b2) at the end.
__global__ __launch_bounds__(256, 3) void edge_mfma_kernel(
    const float* __restrict__ p, const unsigned short* __restrict__ w2p,
    const float* __restrict__ b2, const unsigned short* __restrict__ csrp,
    const int* __restrict__ offs, const int* __restrict__ cur,
    float* __restrict__ out)
{
    int wid = threadIdx.x >> 6, lane = threadIdx.x & 63;
    int node = blockIdx.x * 4 + wid;
    int r31 = lane & 31;          // A-row (edge slot) AND C-col
    int kh  = lane >> 5;          // k-half: k = kh*8 + j

    s16x8 B[8];
    #pragma unroll
    for (int t = 0; t < 8; ++t)
        B[t] = *(const s16x8*)(w2p + (size_t)(t * 64 + lane) * 8);

    float b2r[8];
    #pragma unroll
    for (int t = 0; t < 8; ++t) b2r[t] = b2[t * 32 + r31];

    float pd[8];
    {
        float4 q0 = *(const float4*)(p + node * HID + kh * 8);
        float4 q1 = *(const float4*)(p + node * HID + kh * 8 + 4);
        pd[0] = q0.x; pd[1] = q0.y; pd[2] = q0.z; pd[3] = q0.w;
        pd[4] = q1.x; pd[5] = q1.y; pd[6] = q1.z; pd[7] = q1.w;
    }

    int rs = offs[node], re = offs[node + 1];
    int npad = re - cur[node];    // cur[node] = rs + (deg+1) after scatter

    float racc[8] = {0.f, 0.f, 0.f, 0.f, 0.f, 0.f, 0.f, 0.f};

    for (int pos = rs; pos < re; pos += 32) {
        int s = csrp[pos + r31];             // zero-extended ushort
        bool pad = (s == 0xFFFF);
        int sp = pad ? node : s;
        const float* ps = p + sp * HID + kh * 8;
        float4 a0 = *(const float4*)ps;
        float4 a1 = *(const float4*)(ps + 4);
        float av[8] = {a0.x, a0.y, a0.z, a0.w, a1.x, a1.y, a1.z, a1.w};
        s16x8 Ahi, Alo;
        #pragma unroll
        for (int j = 0; j < 8; ++j) {
            float hv = pad ? 0.f : fmaxf(av[j] + pd[j], 0.f);
            __hip_bfloat16 hb = __float2bfloat16(hv);
            Ahi[j] = __builtin_bit_cast(short, hb);
            __hip_bfloat16 lb = __float2bfloat16(hv - __bfloat162float(hb));
            Alo[j] = __builtin_bit_cast(short, lb);
        }
        #pragma unroll
        for (int t = 0; t < 8; ++t) {
            f32x16 C = {0.f,0.f,0.f,0.f,0.f,0.f,0.f,0.f,
                        0.f,0.f,0.f,0.f,0.f,0.f,0.f,0.f};
            C = __builtin_amdgcn_mfma_f32_32x32x16_bf16(Ahi, B[t], C, 0, 0, 0);
            C = __builtin_amdgcn_mfma_f32_32x32x16_bf16(Alo, B[t], C, 0, 0, 0);
            float bb = b2r[t];
            float ss = 0.f;
            #pragma unroll
            for (int r = 0; r < 16; ++r) ss += fmaxf(C[r] + bb, 0.f);
            racc[t] += ss;
        }
    }

    #pragma unroll
    for (int t = 0; t < 8; ++t) {
        racc[t] += __shfl_xor(racc[t], 32, 64);          // cross lane-half row sum
        racc[t] -= (float)npad * fmaxf(b2r[t], 0.f);     // cancel pad rows
    }

    float* ob = out + (size_t)node * FEAT + r31;
    #pragma unroll
    for (int i = 0; i < 4; ++i) {
        float v = kh ? racc[4 + i] : racc[i];            // static indices only
        ob[(kh * 4 + i) * 32] = v;
    }
}

// ---------------- readout GEMM1 partials: y1part[kb][256][64] ----------------
__global__ __launch_bounds__(256) void ro1_kernel(const float* __restrict__ y,
                                                  const float* __restrict__ w1,
                                                  float* __restrict__ y1part) {
    int mb = blockIdx.x >> 5;            // 0..15
    int kb = blockIdx.x & 31;            // 0..31
    int t = threadIdx.x;
    int ks = t >> 6;                     // wave 0..3
    int lane = t & 63;                   // n column AND k-offset

    float acc[16];
    #pragma unroll
    for (int m = 0; m < 16; ++m) acc[m] = 0.f;

    int kslice = kb * 1024 + ks * 256;
    for (int c4 = 0; c4 < 4; ++c4) {
        int k0 = kslice + c4 * 64;
        float yv[16];
        #pragma unroll
        for (int m = 0; m < 16; ++m)
            yv[m] = y[(size_t)(mb * 16 + m) * 32768 + k0 + lane];   // coalesced
        const float* wp = w1 + (size_t)k0 * 64 + lane;
        #pragma unroll 8
        for (int kk = 0; kk < 64; ++kk) {
            float wv = wp[(size_t)kk * 64];                          // coalesced
            #pragma unroll
            for (int m = 0; m < 16; ++m) {
                float ys = __int_as_float(
                    __builtin_amdgcn_readlane(__float_as_int(yv[m]), kk));
                acc[m] = fmaf(ys, wv, acc[m]);
            }
        }
    }

    __shared__ float red[4368];          // 256*17 + pad
    #pragma unroll
    for (int m = 0; m < 16; ++m) red[t * 17 + m] = acc[m];
    __syncthreads();
    #pragma unroll
    for (int i = 0; i < 4; ++i) {
        int u = t + i * 256;
        int m = u >> 6, nn = u & 63;
        float v = red[nn * 17 + m] + red[(64 + nn) * 17 + m]
                + red[(128 + nn) * 17 + m] + red[(192 + nn) * 17 + m];
        y1part[(size_t)kb * 16384 + (mb * 16 + m) * 64 + nn] = v;   // race-free
    }
}

// ---------------- combine partials + bias + relu ----------------
__global__ void relub_kernel(const float* __restrict__ y1part, const float* __restrict__ b1,
                             float* __restrict__ y1) {
    int i = blockIdx.x * 256 + threadIdx.x;
    float s = b1[i & 63];
    #pragma unroll 8
    for (int kb = 0; kb < 32; ++kb) s += y1part[(size_t)kb * 16384 + i];
    y1[i] = fmaxf(s, 0.f);
}

// ---------------- readout GEMM2: out = relu(y1[256,64] @ w2[64,16384] + b2) ----------------
__global__ __launch_bounds__(256) void ro2_kernel(const float* __restrict__ y1,
                                                  const float* __restrict__ w2,
                                                  const float* __restrict__ b2,
                                                  float* __restrict__ out) {
    __shared__ float yls[64 * 68];
    int mt = blockIdx.x >> 6;            // 4 m-tiles of 64
    int nt = blockIdx.x & 63;            // 64 n-tiles of 256
    int t = threadIdx.x;
    for (int u = t; u < 4096; u += 256) {
        int row = u >> 6, col = u & 63;
        yls[row * 68 + col] = y1[(mt * 64 + row) * 64 + col];
    }
    __syncthreads();

    int n = nt * 256 + t;
    float w2r[64];
    #pragma unroll
    for (int jj = 0; jj < 64; ++jj) w2r[jj] = w2[(size_t)jj * 16384 + n];
    float bb = b2[n];
    for (int m = 0; m < 64; ++m) {
        float acc = bb;
        const float* yr = &yls[m * 68];
        #pragma unroll
        for (int jj = 0; jj < 64; jj += 4) {
            float4 yv = *(const float4*)(yr + jj);
            acc = fmaf(yv.x, w2r[jj],     acc);
            acc = fmaf(yv.y, w2r[jj + 1], acc);
            acc = fmaf(yv.z, w2r[jj + 2], acc);
            acc = fmaf(yv.w, w2r[jj + 3], acc);
        }
        out[(size_t)(mt * 64 + m) * 16384 + n] = fmaxf(acc, 0.f);
    }
}

extern "C" void kernel_launch(void* const* d_in, const int* in_sizes, int n_in,
                              void* d_out, int out_size, void* d_ws, size_t ws_size,
                              hipStream_t stream) {
    (void)in_sizes; (void)n_in; (void)out_size; (void)ws_size;
    const float* x      = (const float*)d_in[0];
    const int*   ei     = (const int*)d_in[1];     // [2, NE] : row0 src, row1 dst
    const float* mp1_w1 = (const float*)d_in[2];
    const float* mp1_b1 = (const float*)d_in[3];
    const float* mp1_w2 = (const float*)d_in[4];
    const float* mp1_b2 = (const float*)d_in[5];
    const float* mp2_w1 = (const float*)d_in[6];
    const float* mp2_b1 = (const float*)d_in[7];
    const float* mp2_w2 = (const float*)d_in[8];
    const float* mp2_b2 = (const float*)d_in[9];
    const float* ro_w1  = (const float*)d_in[10];
    const float* ro_b1  = (const float*)d_in[11];
    const float* ro_w2  = (const float*)d_in[12];
    const float* ro_b2  = (const float*)d_in[13];
    float* out = (float*)d_out;

    // workspace carve-up (~39.3 MB). y1part aliases p (dead by readout).
    float* p      = (float*)d_ws;                    // 524288 floats
    float* y1part = p;                               // alias
    float* x1     = p + 524288;                      // NN*256
    float* y1     = x1 + (size_t)NN * FEAT;          // 16384
    int*   deg    = (int*)(y1 + 16384);              // NN
    int*   offs   = deg + NN;                        // NN+1
    int*   cur    = offs + NN + 1;                   // NN (+3 pad for 16B align)
    unsigned short* csrp = (unsigned short*)(cur + NN + 3);  // CSR_CAP
    unsigned short* w2p1 = csrp + CSR_CAP;           // 4096 (16B aligned)
    unsigned short* w2p2 = w2p1 + 4096;              // 4096

    const int* src = ei;
    const int* dst = ei + NE;

    hipMemsetAsync(deg, 0, NN * sizeof(int), stream);
    hipMemsetAsync(csrp, 0xFF, (size_t)CSR_CAP * 2, stream);

    hist_kernel<<<NE / 256, 256, 0, stream>>>(dst, deg);
    scan_kernel<<<1, 1024, 0, stream>>>(deg, offs, cur);
    scatter_kernel<<<(NE + NN) / 256, 256, 0, stream>>>(src, dst, cur, csrp);
    prepack_w2<<<1, 512, 0, stream>>>(mp1_w2, w2p1);
    prepack_w2<<<1, 512, 0, stream>>>(mp2_w2, w2p2);

    // layer 1
    pk_kernel<<<(NN * HID) / 256, 256, 0, stream>>>(x, mp1_w1, mp1_b1, p);
    edge_mfma_kernel<<<NN / 4, 256, 0, stream>>>(p, w2p1, mp1_b2, csrp, offs, cur, x1);
    // layer 2
    pk_kernel<<<(NN * HID) / 256, 256, 0, stream>>>(x1, mp2_w1, mp2_b1, p);
    edge_mfma_kernel<<<NN / 4, 256, 0, stream>>>(p, w2p2, mp2_b2, csrp, offs, cur, x1);

    // readout (p dead; y1part reuses its storage)
    ro1_kernel<<<512, 256, 0, stream>>>(x1, ro_w1, y1part);
    relub_kernel<<<64, 256, 0, stream>>>(y1part, ro_b1, y1);
    ro2_kernel<<<256, 256, 0, stream>>>(y1, ro_w2, ro_b2, out);
}